// Round 1
// 697.996 us; speedup vs baseline: 1.1461x; 1.1461x over previous
//
#include <hip/hip_runtime.h>
#include <hip/hip_bf16.h>
#include <math.h>

#define N_NODES 500000
#define DIM 256
#define ADIM 64
#define NG 512
#define NBLK 7813   // ceil(500000/64)

typedef __attribute__((ext_vector_type(8))) short short8;
typedef __attribute__((ext_vector_type(4))) float floatx4;

__device__ inline unsigned short f2bf(float f) {
    union { float f; unsigned int u; } v; v.f = f;
    unsigned int u = v.u;
    unsigned int r = u + 0x7FFFu + ((u >> 16) & 1u);   // RNE
    return (unsigned short)(r >> 16);
}

// packed fp32 pair -> 2x bf16 (RNE) in one u32 (v_cvt_pk_bf16_f32)
__device__ inline unsigned pk_bf2(float a, float b) {
    __hip_bfloat162 h = __float22bfloat162_rn(make_float2(a, b));
    union { __hip_bfloat162 h; unsigned u; } cv; cv.h = h;
    return cv.u;
}

// tanh via exp2 pipe: ~7 instr vs libm tanhf ~20+. |err| few ulp.
__device__ inline float tanh_fast(float xv) {
    float e = __expf(2.0f * fabsf(xv));              // inf-safe: rcp(inf)=0 -> 1
    float r = 1.0f - 2.0f * __builtin_amdgcn_rcpf(e + 1.0f);
    return copysignf(r, xv);
}

// ---------------- prep: transpose W_out, pre-convert W_att to bf16,
//                  compute c = ||ctx||_1, zero accum+ssum
__global__ __launch_bounds__(256) void k_prep(const float* __restrict__ W_out,
                                              const float* __restrict__ W_att,
                                              const float* __restrict__ ctx,
                                              float* __restrict__ Wt_out,
                                              unsigned short* __restrict__ Wbf,
                                              float* __restrict__ cnorm,
                                              float* __restrict__ zero_base) {
    int b = blockIdx.x, t = threadIdx.x;
    if (b < 256) {                      // transpose W_out -> Wt[d][o]
        int idx = b * 256 + t;
        int o = idx >> 8, d = idx & 255;
        Wt_out[d * DIM + o] = W_out[idx];
    } else if (b < 320) {               // W_att -> bf16 (once, not per-block)
        int idx = (b - 256) * 256 + t;
        Wbf[idx] = f2bf(W_att[idx]);
    } else if (b < 834) {               // zero accum[512*256] + ssum[512]
        int idx = (b - 320) * 256 + t;  // 514*256 == 131584 exactly
        zero_base[idx] = 0.f;
    } else if (t == 0) {                // c = ||ctx||_1 (global exp offset)
        float s = 0.f;
        for (int k = 0; k < ADIM; ++k) s += fabsf(ctx[k]);
        *cnorm = s;
    }
}

// ---------------- fused: scores (MFMA) + exp + weighted pooling, one x pass.
// 64 nodes/block, 256 threads (4 waves). LDS tile xs[chunk][node][40] keeps the
// proven stride-40 bank layout; chunk stride padded to 65 rows so pooling reads
// (per-wave: node fixed, lane -> dim) land ~2-way instead of 8-way.
__global__ __launch_bounds__(256, 3) void k_fused(const float* __restrict__ x,
                                                  const unsigned short* __restrict__ Wbf,
                                                  const float* __restrict__ b_att,
                                                  const float* __restrict__ ctx,
                                                  const int* __restrict__ batch,
                                                  const float* __restrict__ cnorm,
                                                  float* __restrict__ accum,   // [NG][DIM]
                                                  float* __restrict__ ssum) {  // [NG]
    __shared__ __align__(16) unsigned short xs[8][65][40];
    __shared__ float sacc[4][64];
    __shared__ float pbuf[64];
    __shared__ int   gbuf[64];
    __shared__ __align__(16) float redp[4][64][4];

    const int t = threadIdx.x;
    const int wave = t >> 6;
    const int lane = t & 63;
    const int quad = lane >> 4;
    const int lcol = lane & 15;
    const int base = blockIdx.x * 64;
    const float cn = *cnorm;

    // B fragments straight from pre-converted bf16 W (L2-resident)
    short8 bfrag[8];
    {
        const unsigned short* wr = Wbf + (size_t)(16 * wave + lcol) * DIM + quad * 8;
#pragma unroll
        for (int s = 0; s < 8; ++s) bfrag[s] = *(const short8*)(wr + s * 32);
    }

    // --- stage full 64x256 tile as bf16 (single barrier)
    const int srow = t >> 2;
    const int sk = (t & 3) * 4;
    const int node_s = base + srow;
    const bool valid = node_s < N_NODES;
    const float* xrow = x + (size_t)node_s * DIM;

    float4 h0[8], h1[8];
#pragma unroll
    for (int s = 0; s < 8; ++s) { h0[s] = make_float4(0.f, 0.f, 0.f, 0.f); h1[s] = h0[s]; }
    if (valid) {
#pragma unroll
        for (int s = 0; s < 8; ++s) {
            h0[s] = *(const float4*)(xrow + s * 32 + sk);
            h1[s] = *(const float4*)(xrow + s * 32 + sk + 16);
        }
    }
#pragma unroll
    for (int s = 0; s < 8; ++s) {
        uint2 w0, w1;
        w0.x = pk_bf2(h0[s].x, h0[s].y); w0.y = pk_bf2(h0[s].z, h0[s].w);
        w1.x = pk_bf2(h1[s].x, h1[s].y); w1.y = pk_bf2(h1[s].z, h1[s].w);
        *(uint2*)&xs[s][srow][sk]      = w0;
        *(uint2*)&xs[s][srow][sk + 16] = w1;
    }
    __syncthreads();

    // --- MFMA: logits[node][attn]
    floatx4 acc[4];
#pragma unroll
    for (int mt = 0; mt < 4; ++mt) acc[mt] = (floatx4)0.f;
#pragma unroll
    for (int s = 0; s < 8; ++s) {
#pragma unroll
        for (int mt = 0; mt < 4; ++mt) {
            short8 afrag = *(const short8*)&xs[s][mt * 16 + lcol][quad * 8];
            acc[mt] = __builtin_amdgcn_mfma_f32_16x16x32_bf16(afrag, bfrag[s], acc[mt], 0, 0, 0);
        }
    }

    // --- scores epilogue: s[node] = sum_col ctx*tanh(logit + b)
    const float ctxv = ctx[16 * wave + lcol];
    const float bv = b_att[16 * wave + lcol];
#pragma unroll
    for (int mt = 0; mt < 4; ++mt) {
#pragma unroll
        for (int r = 0; r < 4; ++r) {
            float v = ctxv * tanh_fast(acc[mt][r] + bv);
            v += __shfl_xor(v, 1);
            v += __shfl_xor(v, 2);
            v += __shfl_xor(v, 4);
            v += __shfl_xor(v, 8);
            if (lcol == 0) sacc[wave][mt * 16 + quad * 4 + r] = v;
        }
    }
    __syncthreads();
    if (t < 64) {
        float sres = (sacc[0][t] + sacc[1][t]) + (sacc[2][t] + sacc[3][t]);
        int node = base + t;
        bool v = node < N_NODES;
        pbuf[t] = v ? __expf(sres - cn) : 0.f;    // no segment max needed: |s| <= cn
        gbuf[t] = batch[v ? node : (N_NODES - 1)];
    }
    __syncthreads();

    // --- weighted pooling: accum[g][d] += sum_i p_i * x[i][d]  (bf16 tile)
    const int g0 = gbuf[0];
    const int g1 = gbuf[63];
    const int ps = lane >> 3;          // chunk
    const int pc = (lane & 7) * 4;     // col in chunk; dim d = lane*4 + k
    for (int g = g0; g <= g1; ++g) {   // usually 1 iter; 2 at segment boundaries
        float4 a4 = make_float4(0.f, 0.f, 0.f, 0.f);
#pragma unroll 4
        for (int j = 0; j < 16; ++j) {
            int i = (wave << 4) + j;
            float wp = (gbuf[i] == g) ? pbuf[i] : 0.f;   // wave-uniform
            if (wp != 0.f) {
                uint2 v = *(const uint2*)&xs[ps][i][pc];
                a4.x += wp * __uint_as_float(v.x << 16);
                a4.y += wp * __uint_as_float(v.x & 0xffff0000u);
                a4.z += wp * __uint_as_float(v.y << 16);
                a4.w += wp * __uint_as_float(v.y & 0xffff0000u);
            }
        }
        *(float4*)&redp[wave][lane][0] = a4;
        float sp = 0.f;
        if (t < 64) sp = (gbuf[t] == g) ? pbuf[t] : 0.f;
        __syncthreads();
        float r = ((redp[0][t >> 2][t & 3] + redp[1][t >> 2][t & 3]) +
                   (redp[2][t >> 2][t & 3] + redp[3][t >> 2][t & 3]));
        atomicAdd(&accum[(size_t)g * DIM + t], r);
        if (t < 64) {
            sp += __shfl_xor(sp, 1);  sp += __shfl_xor(sp, 2);
            sp += __shfl_xor(sp, 4);  sp += __shfl_xor(sp, 8);
            sp += __shfl_xor(sp, 16); sp += __shfl_xor(sp, 32);
            if (t == 0) atomicAdd(&ssum[g], sp);
        }
        __syncthreads();   // redp reused next g
    }
}

// ---------------- out = (accum/ssum) @ W_out^T + b_out
__global__ __launch_bounds__(256) void k_out(const float* __restrict__ accum,
                                             const float* __restrict__ ssum,
                                             const float* __restrict__ WtOut,
                                             const float* __restrict__ b_out,
                                             float* __restrict__ out) {
    int g = blockIdx.x;
    int t = threadIdx.x;
    __shared__ float pl[256];
    float inv = 1.0f / (ssum[g] + 1e-20f);
    pl[t] = accum[(size_t)g * DIM + t] * inv;
    __syncthreads();
    float acc = b_out[t];
#pragma unroll 4
    for (int d = 0; d < DIM; ++d) acc += pl[d] * WtOut[d * DIM + t];
    out[(size_t)g * DIM + t] = acc;
}

extern "C" void kernel_launch(void* const* d_in, const int* in_sizes, int n_in,
                              void* d_out, int out_size, void* d_ws, size_t ws_size,
                              hipStream_t stream) {
    (void)in_sizes; (void)n_in; (void)out_size; (void)ws_size;
    const float* x     = (const float*)d_in[0];
    const int*   batch = (const int*)d_in[1];
    const float* W_att = (const float*)d_in[2];
    const float* b_att = (const float*)d_in[3];
    const float* ctx   = (const float*)d_in[4];
    const float* W_out = (const float*)d_in[5];
    const float* b_out = (const float*)d_in[6];
    float* out = (float*)d_out;

    // workspace layout (floats), ~840 KB total
    float* accum = (float*)d_ws;                       // 131072  (NG*DIM)
    float* ssum  = accum + 131072;                     // 512
    float* Wt    = ssum + 512;                         // 65536
    unsigned short* Wbf = (unsigned short*)(Wt + 65536); // 16384 ushort (16B-aligned)
    float* cnorm = (float*)(Wbf + 16384);              // 1

    k_prep<<<dim3(835), dim3(256), 0, stream>>>(W_out, W_att, ctx, Wt, Wbf, cnorm, accum);
    k_fused<<<dim3(NBLK), dim3(256), 0, stream>>>(x, Wbf, b_att, ctx, batch, cnorm, accum, ssum);
    k_out<<<dim3(NG), dim3(256), 0, stream>>>(accum, ssum, Wt, b_out, out);
}